// Round 1
// baseline (1416.613 us; speedup 1.0000x reference)
//
#include <hip/hip_runtime.h>

// EdgeFeature kNN (DGCNN): B=4, D=64, N=4096, K=16, fp32 in/out.
// Ranking replicates the numpy fp32 reference pipeline bit-exactly:
//   sq_n  = numpy pairwise_sum (8-accumulator unroll) of fl(x_d^2)
//   dot   = sequential over d of  a = fmaf(x_d, y_d, a)   (einsum axpy w/ FMA)
//   d2    = fl(fl(sq_n + sq_m) - fl(2*dot));  dist = fl(sqrt(max(d2,0)))
//   order = (dist_f32, index) lexicographic (stable top_k tie-break)
// Key pack: (dist_bits << 32) | m  -> one u64 compare == lex order.
//
// R8: loop-flip of the partial kernel. R7 was scalar-load latency-bound
//     (SGPR_Count=32 -> <=2 SMEM batches in flight, lgkmcnt(0) drains,
//     VALUBusy 34%). Now candidates are processed d-major in groups of 8
//     directly from the ORIGINAL pc[b][d][m] layout: per d-step one
//     contiguous 32B wave-uniform load (s_load_dwordx8) feeds 8
//     independent FMA accumulator chains (ILP breaks the 64-long dep
//     chain). Insertion is a branchless u64 min/max ladder (cmp reused
//     for both selects, no 'placed' flags, self handled by ~0 sentinel).
//     pcT/transpose kernel removed: query rows load coalesced from pc.
//     Per-candidate FMA order (d ascending) unchanged -> bit-exact.

#define BATCH 4
#define DIMS 64
#define NPTS 4096
#define KNN 16
#define NCHUNK 16
#define CHLEN 256      // NPTS / NCHUNK
#define GSZ 8          // candidates per group (8 fp32 = one s_load_dwordx8)

typedef unsigned long long u64;
typedef unsigned int u32;

// ---- kernel 0: per-point squared norm, numpy pairwise_sum order ---------
__global__ __launch_bounds__(256) void ef_sq_kernel(const float* __restrict__ pc,
                                                    float* __restrict__ sq) {
    int gid = blockIdx.x * 256 + threadIdx.x;     // b*NPTS + n
    int b = gid >> 12;
    int n = gid & (NPTS - 1);
    const float* p = pc + (size_t)b * DIMS * NPTS + n;
    float r[8];
#pragma unroll
    for (int j = 0; j < 8; ++j) {
        float v = p[(size_t)j * NPTS];
        r[j] = __fmul_rn(v, v);
    }
#pragma unroll
    for (int i = 8; i < DIMS; i += 8) {
#pragma unroll
        for (int j = 0; j < 8; ++j) {
            float v = p[(size_t)(i + j) * NPTS];
            r[j] = __fadd_rn(r[j], __fmul_rn(v, v));
        }
    }
    float t01 = __fadd_rn(r[0], r[1]);
    float t23 = __fadd_rn(r[2], r[3]);
    float t45 = __fadd_rn(r[4], r[5]);
    float t67 = __fadd_rn(r[6], r[7]);
    sq[gid] = __fadd_rn(__fadd_rn(t01, t23), __fadd_rn(t45, t67));
}

// ---- kernel 1: per-(row, chunk) partial top-16, d-major candidate scan --
__global__ __launch_bounds__(256) void ef_knn_partial(const float* __restrict__ pc,
                                                      const float* __restrict__ sq,
                                                      u64* __restrict__ pKey) {
    const float* pcA = (const float*)__builtin_assume_aligned(pc, 256);
    const float* sqA = (const float*)__builtin_assume_aligned(sq, 256);
    int tid = threadIdx.x;
    int r = blockIdx.x * 256 + tid;               // global row: b*NPTS + n
    int c = blockIdx.y;
    int b = r >> 12;
    int n = r & (NPTS - 1);

    // per-lane query row: lane n reads pc[b][d][n] -> coalesced across lanes
    const float* xp = pcA + (size_t)b * DIMS * NPTS + n;
    float xr[DIMS];
#pragma unroll
    for (int d = 0; d < DIMS; ++d) xr[d] = xp[(size_t)d * NPTS];
    float sqn = sqA[r];

    u64 key[KNN];
#pragma unroll
    for (int j = 0; j < KNN; ++j) key[j] = ~0ULL;

    int m0 = c * CHLEN;
    const float* cb = pcA + (size_t)b * DIMS * NPTS + m0;   // wave-uniform
    const float* sqb = sqA + b * NPTS + m0;                 // wave-uniform

#pragma unroll 2
    for (int g = 0; g < CHLEN; g += GSZ) {
        float acc[GSZ];
#pragma unroll
        for (int j = 0; j < GSZ; ++j) acc[j] = 0.f;
        // d-major: one contiguous 32B uniform load feeds 8 independent
        // FMA chains; each chain's d-order is sequential (bit-exact).
#pragma unroll
        for (int d = 0; d < DIMS; ++d) {
            const float* row = cb + (size_t)d * NPTS + g;
#pragma unroll
            for (int j = 0; j < GSZ; ++j)
                acc[j] = fmaf(xr[d], row[j], acc[j]);
        }
#pragma unroll
        for (int j = 0; j < GSZ; ++j) {
            int m = m0 + g + j;
            float sqm = sqb[g + j];
            float t1 = __fadd_rn(sqn, sqm);
            float d2 = __fsub_rn(t1, __fmul_rn(2.0f, acc[j]));
            float dist = __fsqrt_rn(fmaxf(d2, 0.f));
            u64 cand = ((u64)__float_as_uint(dist) << 32) | (u64)(u32)m;
            cand = (m == n) ? ~0ULL : cand;       // self -> +inf sentinel
            // branchless insertion: running-max ladder, cmp reused
            u64 hi = cand;
#pragma unroll
            for (int p = 0; p < KNN; ++p) {
                u64 kp = key[p];
                bool lt = kp < hi;
                u64 lo = lt ? kp : hi;
                u64 h2 = lt ? hi : kp;
                key[p] = lo;
                hi = h2;
            }
        }
    }

    u64* dst = pKey + ((size_t)r * NCHUNK + c) * KNN;
#pragma unroll
    for (int j = 0; j < KNN; ++j) dst[j] = key[j];
}

// ---- kernel 2: merge 16 sorted partial lists per row, emit idx as float -
__global__ __launch_bounds__(256) void ef_knn_merge(const u64* __restrict__ pKey,
                                                    float* __restrict__ outIdxF) {
    int r = blockIdx.x * 256 + threadIdx.x;       // b*NPTS + n, 16384 rows
    const u64* src = pKey + (size_t)r * (NCHUNK * KNN);
    u64 key[KNN];
#pragma unroll
    for (int j = 0; j < KNN; ++j) key[j] = src[j];   // chunk 0 is sorted
    for (int c = 1; c < NCHUNK; ++c) {
#pragma unroll
        for (int j = 0; j < KNN; ++j) {
            u64 cand = src[c * KNN + j];
            if (cand < key[KNN - 1]) {
                bool placed = false;
#pragma unroll
                for (int p = KNN - 1; p >= 1; --p) {
                    if (!placed) {
                        if (cand < key[p - 1]) {
                            key[p] = key[p - 1];
                        } else {
                            key[p] = cand;
                            placed = true;
                        }
                    }
                }
                if (!placed) key[0] = cand;
            }
        }
    }
#pragma unroll
    for (int j = 0; j < KNN; ++j)
        outIdxF[(size_t)r * KNN + j] = (float)(u32)(key[j] & 0xFFFFFFFFu);
}

// ---- kernel 3: edge features -------------------------------------------
// out[b][ch][n][k]: ch<64 -> central, ch>=64 -> neighbor - central.
__global__ __launch_bounds__(256) void ef_edge_kernel(const float* __restrict__ pc,
                                                      const float* __restrict__ idxF,
                                                      float* __restrict__ out) {
    int gid = blockIdx.x * 256 + threadIdx.x;      // B*N*K = 262144
    int b = gid >> 16;                             // N*K = 65536
    int nk = gid & 65535;
    int n = nk >> 4;
    int m = (int)idxF[gid];
    const float* pcb = pc + (size_t)b * DIMS * NPTS;
    float* ob = out + (size_t)b * 2 * DIMS * NPTS * KNN;
#pragma unroll
    for (int d = 0; d < DIMS; ++d) {
        float cv = pcb[(size_t)d * NPTS + n];
        float nv = pcb[(size_t)d * NPTS + m];
        ob[(size_t)d * (NPTS * KNN) + nk] = cv;
        ob[(size_t)(DIMS + d) * (NPTS * KNN) + nk] = nv - cv;
    }
}

extern "C" void kernel_launch(void* const* d_in, const int* in_sizes, int n_in,
                              void* d_out, int out_size, void* d_ws, size_t ws_size,
                              hipStream_t stream) {
    const float* pc = (const float*)d_in[0];
    float* out = (float*)d_out;

    // Scratch inside the edge-feature region of d_out (fully overwritten by
    // ef_edge_kernel): pKey 33.5 MB ++ sq 64 KB  (< 134 MB).
    u64* pKey = (u64*)d_out;                          // [B*N][NCHUNK][KNN] u64
    float* sq = out + 8388608;                        // 16384 floats
    float* outIdxF = out + (size_t)BATCH * 2 * DIMS * NPTS * KNN; // 33,554,432

    ef_sq_kernel<<<(BATCH * NPTS) / 256, 256, 0, stream>>>(pc, sq);
    ef_knn_partial<<<dim3((BATCH * NPTS) / 256, NCHUNK), 256, 0, stream>>>(pc, sq, pKey);
    ef_knn_merge<<<(BATCH * NPTS) / 256, 256, 0, stream>>>(pKey, outIdxF);
    ef_edge_kernel<<<(BATCH * NPTS * KNN) / 256, 256, 0, stream>>>(pc, outIdxF, out);
}

// Round 2
// 434.161 us; speedup vs baseline: 3.2629x; 3.2629x over previous
//
#include <hip/hip_runtime.h>

// EdgeFeature kNN (DGCNN): B=4, D=64, N=4096, K=16, fp32 in/out.
// Ranking replicates the numpy fp32 reference pipeline bit-exactly:
//   sq_n  = numpy pairwise_sum (8-accumulator unroll) of fl(x_d^2)
//   dot   = sequential over d of  a = fmaf(x_d, y_d, a)   (einsum axpy w/ FMA)
//   d2    = fl(fl(sq_n + sq_m) - fl(2*dot));  dist = fl(sqrt(max(d2,0)))
//   order = (dist_f32, index) lexicographic (stable top_k tie-break)
// Key pack: (dist_bits << 32) | m  -> one u64 compare == lex order (no ties).
//
// R9: R8's scalar-path loads (SGPR=112, occupancy 11%, lgkmcnt serialization)
//     replaced by an LDS-staged candidate tile shared by the block's 4 waves.
//     Chunk = 128 candidates -> tile[64][128] f32 = 32 KB staged once, then
//     uniform-address ds_read_b128 (broadcast, conflict-free, ~120cy, deeply
//     pipelined by compiler lgkmcnt scheduling) feeds 8 independent FMA
//     accumulator chains (ILP covers the 4cy FMA latency). Branchless u64
//     ladder kept (wave-level skip never fires within a fresh 128-chunk).
//     __launch_bounds__(256,3): VGPR cap 170 -> 3 WG/CU (LDS allows 4).
//     Merge parallelized 4 lanes/row + bitonic shfl combine (NCHUNK=32).
//     Per-candidate FMA d-order unchanged -> bit-exact.

#define BATCH 4
#define DIMS 64
#define NPTS 4096
#define KNN 16
#define NCHUNK 32
#define CHLEN 128      // NPTS / NCHUNK
#define GSZ 8          // candidates per group: 8 independent FMA chains

typedef unsigned long long u64;
typedef unsigned int u32;

// ---- kernel 0: per-point squared norm, numpy pairwise_sum order ---------
__global__ __launch_bounds__(256) void ef_sq_kernel(const float* __restrict__ pc,
                                                    float* __restrict__ sq) {
    int gid = blockIdx.x * 256 + threadIdx.x;     // b*NPTS + n
    int b = gid >> 12;
    int n = gid & (NPTS - 1);
    const float* p = pc + (size_t)b * DIMS * NPTS + n;
    float r[8];
#pragma unroll
    for (int j = 0; j < 8; ++j) {
        float v = p[(size_t)j * NPTS];
        r[j] = __fmul_rn(v, v);
    }
#pragma unroll
    for (int i = 8; i < DIMS; i += 8) {
#pragma unroll
        for (int j = 0; j < 8; ++j) {
            float v = p[(size_t)(i + j) * NPTS];
            r[j] = __fadd_rn(r[j], __fmul_rn(v, v));
        }
    }
    float t01 = __fadd_rn(r[0], r[1]);
    float t23 = __fadd_rn(r[2], r[3]);
    float t45 = __fadd_rn(r[4], r[5]);
    float t67 = __fadd_rn(r[6], r[7]);
    sq[gid] = __fadd_rn(__fadd_rn(t01, t23), __fadd_rn(t45, t67));
}

// ---- kernel 1: per-(row, chunk) partial top-16, LDS-staged candidates ---
__global__ __launch_bounds__(256, 3) void ef_knn_partial(const float* __restrict__ pc,
                                                         const float* __restrict__ sq,
                                                         u64* __restrict__ pKey) {
    __shared__ float tile[DIMS][CHLEN];           // 32 KB candidate tile
    __shared__ float tileSq[CHLEN];
    int tid = threadIdx.x;
    int r = blockIdx.x * 256 + tid;               // global row: b*NPTS + n
    int c = blockIdx.y;
    int b = (blockIdx.x * 256) >> 12;             // uniform per block
    int n = r & (NPTS - 1);
    int m0 = c * CHLEN;
    const float* pcb = pc + (size_t)b * DIMS * NPTS;

    // per-lane query row: lane n reads pc[b][d][n] -> coalesced across lanes
    float xr[DIMS];
#pragma unroll
    for (int d = 0; d < DIMS; ++d) xr[d] = pcb[(size_t)d * NPTS + n];
    float sqn = sq[r];

    // stage candidate tile [64][128] + its sq row (coalesced float4)
#pragma unroll
    for (int i = 0; i < 8; ++i) {
        int idx = tid + i * 256;                  // float4 slot, 2048 total
        int d = idx >> 5;                         // 32 float4 per row
        int mq = idx & 31;
        float4 v = *(const float4*)(pcb + (size_t)d * NPTS + m0 + mq * 4);
        *(float4*)&tile[d][mq * 4] = v;
    }
    if (tid < CHLEN / 4)
        *(float4*)&tileSq[tid * 4] =
            *(const float4*)(sq + (size_t)b * NPTS + m0 + tid * 4);
    __syncthreads();

    u64 key[KNN];
#pragma unroll
    for (int j = 0; j < KNN; ++j) key[j] = ~0ULL;

    for (int g = 0; g < CHLEN; g += GSZ) {
        float acc[GSZ];
#pragma unroll
        for (int j = 0; j < GSZ; ++j) acc[j] = 0.f;
        // d-major: two uniform ds_read_b128 per d-step (broadcast) feed 8
        // independent FMA chains; per-candidate d-order sequential (exact).
#pragma unroll
        for (int d = 0; d < DIMS; ++d) {
            float xv = xr[d];
            float4 lo = *(const float4*)&tile[d][g];
            float4 hi = *(const float4*)&tile[d][g + 4];
            acc[0] = fmaf(xv, lo.x, acc[0]);
            acc[1] = fmaf(xv, lo.y, acc[1]);
            acc[2] = fmaf(xv, lo.z, acc[2]);
            acc[3] = fmaf(xv, lo.w, acc[3]);
            acc[4] = fmaf(xv, hi.x, acc[4]);
            acc[5] = fmaf(xv, hi.y, acc[5]);
            acc[6] = fmaf(xv, hi.z, acc[6]);
            acc[7] = fmaf(xv, hi.w, acc[7]);
        }
        float4 sq_lo = *(const float4*)&tileSq[g];
        float4 sq_hi = *(const float4*)&tileSq[g + 4];
        float sqv[GSZ] = {sq_lo.x, sq_lo.y, sq_lo.z, sq_lo.w,
                          sq_hi.x, sq_hi.y, sq_hi.z, sq_hi.w};
#pragma unroll
        for (int j = 0; j < GSZ; ++j) {
            int m = m0 + g + j;
            float t1 = __fadd_rn(sqn, sqv[j]);
            float d2 = __fsub_rn(t1, __fmul_rn(2.0f, acc[j]));
            float dist = __fsqrt_rn(fmaxf(d2, 0.f));
            u64 cand = ((u64)__float_as_uint(dist) << 32) | (u64)(u32)m;
            cand = (m == n) ? ~0ULL : cand;       // self -> +inf sentinel
            // branchless insertion: running-max ladder, cmp reused
            u64 hi2 = cand;
#pragma unroll
            for (int p = 0; p < KNN; ++p) {
                u64 kp = key[p];
                bool lt = kp < hi2;
                u64 lo2 = lt ? kp : hi2;
                u64 up = lt ? hi2 : kp;
                key[p] = lo2;
                hi2 = up;
            }
        }
    }

    u64* dst = pKey + ((size_t)r * NCHUNK + c) * KNN;
#pragma unroll
    for (int j = 0; j < KNN; ++j) dst[j] = key[j];
}

// ---- kernel 2: merge 32 sorted partial lists per row, 4 lanes per row ---
// Each lane ladder-merges 8 chunks (128 u64), then 2 rounds of shfl_xor +
// Batcher bitonic merge combine the 4 sorted 16-lists. u64 keys are
// tie-free (index in low bits) so plain < is the exact total order.
__global__ __launch_bounds__(256) void ef_knn_merge(const u64* __restrict__ pKey,
                                                    float* __restrict__ outIdxF) {
    int t = blockIdx.x * 256 + threadIdx.x;       // 65536 = rows*4
    int r = t >> 2;
    int s = t & 3;
    const u64* src = pKey + ((size_t)r * NCHUNK + s * (NCHUNK / 4)) * KNN;
    u64 key[KNN];
#pragma unroll
    for (int j = 0; j < KNN; ++j) key[j] = src[j];     // first list (sorted)
    for (int i = KNN; i < (NCHUNK / 4) * KNN; ++i) {
        u64 hi2 = src[i];
#pragma unroll
        for (int p = 0; p < KNN; ++p) {
            u64 kp = key[p];
            bool lt = kp < hi2;
            u64 lo2 = lt ? kp : hi2;
            u64 up = lt ? hi2 : kp;
            key[p] = lo2;
            hi2 = up;
        }
    }
#pragma unroll
    for (int mask = 1; mask <= 2; mask <<= 1) {
        u64 oth[KNN];
#pragma unroll
        for (int j = 0; j < KNN; ++j)
            oth[j] = __shfl_xor((unsigned long long)key[j], mask, 64);
        // half-cleaner: lowest 16 of (mine asc, partner desc) -> bitonic
        u64 cc[KNN];
#pragma unroll
        for (int j = 0; j < KNN; ++j) {
            u64 bj = oth[KNN - 1 - j];
            cc[j] = key[j] < bj ? key[j] : bj;
        }
        // bitonic sort of bitonic-16: stages 8,4,2,1
#pragma unroll
        for (int st = 8; st >= 1; st >>= 1) {
#pragma unroll
            for (int j = 0; j < KNN; ++j) {
                if ((j & st) == 0) {
                    u64 a = cc[j], d = cc[j | st];
                    bool lt = a < d;
                    cc[j] = lt ? a : d;
                    cc[j | st] = lt ? d : a;
                }
            }
        }
#pragma unroll
        for (int j = 0; j < KNN; ++j) key[j] = cc[j];
    }
    if (s == 0) {
        float* dstf = outIdxF + (size_t)r * KNN;
#pragma unroll
        for (int j = 0; j < KNN; ++j)
            dstf[j] = (float)(u32)(key[j] & 0xFFFFFFFFu);
    }
}

// ---- kernel 3: edge features -------------------------------------------
// out[b][ch][n][k]: ch<64 -> central, ch>=64 -> neighbor - central.
__global__ __launch_bounds__(256) void ef_edge_kernel(const float* __restrict__ pc,
                                                      const float* __restrict__ idxF,
                                                      float* __restrict__ out) {
    int gid = blockIdx.x * 256 + threadIdx.x;      // B*N*K = 262144
    int b = gid >> 16;                             // N*K = 65536
    int nk = gid & 65535;
    int n = nk >> 4;
    int m = (int)idxF[gid];
    const float* pcb = pc + (size_t)b * DIMS * NPTS;
    float* ob = out + (size_t)b * 2 * DIMS * NPTS * KNN;
#pragma unroll
    for (int d = 0; d < DIMS; ++d) {
        float cv = pcb[(size_t)d * NPTS + n];
        float nv = pcb[(size_t)d * NPTS + m];
        ob[(size_t)d * (NPTS * KNN) + nk] = cv;
        ob[(size_t)(DIMS + d) * (NPTS * KNN) + nk] = nv - cv;
    }
}

extern "C" void kernel_launch(void* const* d_in, const int* in_sizes, int n_in,
                              void* d_out, int out_size, void* d_ws, size_t ws_size,
                              hipStream_t stream) {
    const float* pc = (const float*)d_in[0];
    float* out = (float*)d_out;

    // Scratch inside the edge-feature region of d_out (fully overwritten by
    // ef_edge_kernel): pKey 67.1 MB ++ sq 64 KB  (< 134 MB).
    u64* pKey = (u64*)d_out;                          // [B*N][NCHUNK][KNN] u64
    float* sq = out + 16777216;                       // byte 67,108,864
    float* outIdxF = out + (size_t)BATCH * 2 * DIMS * NPTS * KNN; // 33,554,432

    ef_sq_kernel<<<(BATCH * NPTS) / 256, 256, 0, stream>>>(pc, sq);
    ef_knn_partial<<<dim3((BATCH * NPTS) / 256, NCHUNK), 256, 0, stream>>>(pc, sq, pKey);
    ef_knn_merge<<<(BATCH * NPTS * 4) / 256, 256, 0, stream>>>(pKey, outIdxF);
    ef_edge_kernel<<<(BATCH * NPTS * KNN) / 256, 256, 0, stream>>>(pc, outIdxF, out);
}

// Round 3
// 336.300 us; speedup vs baseline: 4.2124x; 1.2910x over previous
//
#include <hip/hip_runtime.h>

// EdgeFeature kNN (DGCNN): B=4, D=64, N=4096, K=16, fp32 in/out.
// Ranking replicates the numpy fp32 reference pipeline bit-exactly:
//   sq_n  = numpy pairwise_sum (8-accumulator unroll) of fl(x_d^2)
//   dot   = sequential over d of  a = fmaf(x_d, y_d, a)   (einsum axpy w/ FMA)
//   d2    = fl(fl(sq_n + sq_m) - fl(2*dot));  dist = fl(sqrt(max(d2,0)))
//   order = (dist_f32, index) lexicographic (stable top_k tie-break)
// Key pack: (dist_bits << 32) | m. All packed keys are POSITIVE FINITE f64
// bit patterns (dist f32 exponent can never fill f64 exp bits), and for
// positive finite doubles numeric order == bit order. So v_min_f64/
// v_max_f64 (1 instr each) do an exact u64 compare-exchange: 2 instrs vs
// the 5-instr cmp_u64+4*cndmask ladder step. Sentinel = DBL_MAX bits
// 0x7FEFFFFFFFFFFFFF > any real key (even dist=inf packs below it).
//
// R10 (from R9 counters: VGPR=64 -> compiler rematerialized xr[] reloads;
//      ladder = 80/152 VALU instrs; pKey layout uncoalesced both sides):
//   * f64 min/max compare-exchange everywhere (exact, see above)
//   * per-group sort8 (Batcher 19 CE) + bitonic merge into sorted-16:
//     ~14 instr/cand vs 80 for the insertion ladder. Exact: keys are
//     distinct (index in low bits) -> any correct network == ladder.
//   * xr[] pinned with empty asm -> stays resident (no L1 re-reads)
//   * pKey layout [c][r][j]: partial writes and merge reads both become
//     contiguous 128 B/lane, 8 KB/wave segments
//   * merge: 8 lanes/row (2 waves/SIMD), bitonic chunk merges

#define BATCH 4
#define DIMS 64
#define NPTS 4096
#define KNN 16
#define NCHUNK 32
#define CHLEN 128      // NPTS / NCHUNK
#define GSZ 8          // candidates per group: 8 independent FMA chains
#define RN (BATCH * NPTS)
#define MLANES 8       // merge lanes per row
#define MCH (NCHUNK / MLANES)

typedef unsigned long long u64;
typedef unsigned int u32;

__device__ __forceinline__ double sentinel() {
    return __longlong_as_double(0x7FEFFFFFFFFFFFFFLL);   // DBL_MAX bits
}

// ---- kernel 0: per-point squared norm, numpy pairwise_sum order ---------
__global__ __launch_bounds__(256) void ef_sq_kernel(const float* __restrict__ pc,
                                                    float* __restrict__ sq) {
    int gid = blockIdx.x * 256 + threadIdx.x;     // b*NPTS + n
    int b = gid >> 12;
    int n = gid & (NPTS - 1);
    const float* p = pc + (size_t)b * DIMS * NPTS + n;
    float r[8];
#pragma unroll
    for (int j = 0; j < 8; ++j) {
        float v = p[(size_t)j * NPTS];
        r[j] = __fmul_rn(v, v);
    }
#pragma unroll
    for (int i = 8; i < DIMS; i += 8) {
#pragma unroll
        for (int j = 0; j < 8; ++j) {
            float v = p[(size_t)(i + j) * NPTS];
            r[j] = __fadd_rn(r[j], __fmul_rn(v, v));
        }
    }
    float t01 = __fadd_rn(r[0], r[1]);
    float t23 = __fadd_rn(r[2], r[3]);
    float t45 = __fadd_rn(r[4], r[5]);
    float t67 = __fadd_rn(r[6], r[7]);
    sq[gid] = __fadd_rn(__fadd_rn(t01, t23), __fadd_rn(t45, t67));
}

// ---- kernel 1: per-(row, chunk) partial top-16, LDS-staged candidates ---
__global__ __launch_bounds__(256, 3) void ef_knn_partial(const float* __restrict__ pc,
                                                         const float* __restrict__ sq,
                                                         u64* __restrict__ pKey) {
    __shared__ float tile[DIMS][CHLEN];           // 32 KB candidate tile
    __shared__ float tileSq[CHLEN];
    int tid = threadIdx.x;
    int r = blockIdx.x * 256 + tid;               // global row: b*NPTS + n
    int c = blockIdx.y;
    int b = (blockIdx.x * 256) >> 12;             // uniform per block
    int n = r & (NPTS - 1);
    int m0 = c * CHLEN;
    const float* pcb = pc + (size_t)b * DIMS * NPTS;

    // per-lane query row: lane n reads pc[b][d][n] -> coalesced across lanes
    float xr[DIMS];
#pragma unroll
    for (int d = 0; d < DIMS; ++d) xr[d] = pcb[(size_t)d * NPTS + n];
    // pin: forbid rematerialization (R9: compiler re-loaded xr per group)
#pragma unroll
    for (int d = 0; d < DIMS; ++d) asm volatile("" : "+v"(xr[d]));
    float sqn = sq[r];

    // stage candidate tile [64][128] + its sq row (coalesced float4)
#pragma unroll
    for (int i = 0; i < 8; ++i) {
        int idx = tid + i * 256;                  // float4 slot, 2048 total
        int d = idx >> 5;                         // 32 float4 per row
        int mq = idx & 31;
        float4 v = *(const float4*)(pcb + (size_t)d * NPTS + m0 + mq * 4);
        *(float4*)&tile[d][mq * 4] = v;
    }
    if (tid < CHLEN / 4)
        *(float4*)&tileSq[tid * 4] =
            *(const float4*)(sq + (size_t)b * NPTS + m0 + tid * 4);
    __syncthreads();

    double key[KNN];
#pragma unroll
    for (int j = 0; j < KNN; ++j) key[j] = sentinel();

    for (int g = 0; g < CHLEN; g += GSZ) {
        float acc[GSZ];
#pragma unroll
        for (int j = 0; j < GSZ; ++j) acc[j] = 0.f;
        // d-major: two uniform ds_read_b128 per d-step (broadcast) feed 8
        // independent FMA chains; per-candidate d-order sequential (exact).
#pragma unroll
        for (int d = 0; d < DIMS; ++d) {
            float xv = xr[d];
            float4 lo = *(const float4*)&tile[d][g];
            float4 hi = *(const float4*)&tile[d][g + 4];
            acc[0] = fmaf(xv, lo.x, acc[0]);
            acc[1] = fmaf(xv, lo.y, acc[1]);
            acc[2] = fmaf(xv, lo.z, acc[2]);
            acc[3] = fmaf(xv, lo.w, acc[3]);
            acc[4] = fmaf(xv, hi.x, acc[4]);
            acc[5] = fmaf(xv, hi.y, acc[5]);
            acc[6] = fmaf(xv, hi.z, acc[6]);
            acc[7] = fmaf(xv, hi.w, acc[7]);
        }
        float4 sq_lo = *(const float4*)&tileSq[g];
        float4 sq_hi = *(const float4*)&tileSq[g + 4];
        float sqv[GSZ] = {sq_lo.x, sq_lo.y, sq_lo.z, sq_lo.w,
                          sq_hi.x, sq_hi.y, sq_hi.z, sq_hi.w};
        double s[GSZ];
#pragma unroll
        for (int j = 0; j < GSZ; ++j) {
            int m = m0 + g + j;
            float t1 = __fadd_rn(sqn, sqv[j]);
            float d2 = __fsub_rn(t1, __fmul_rn(2.0f, acc[j]));
            float dist = __fsqrt_rn(fmaxf(d2, 0.f));
            u64 cu = ((u64)__float_as_uint(dist) << 32) | (u64)(u32)m;
            double cand = __longlong_as_double((long long)cu);
            s[j] = (m == n) ? sentinel() : cand;   // self -> +max sentinel
        }
        // sort8: Batcher odd-even mergesort, 19 CE (exact u64 order via f64)
#define CE8(i, jj) { double lo_ = fmin(s[i], s[jj]); double hi_ = fmax(s[i], s[jj]); s[i] = lo_; s[jj] = hi_; }
        CE8(0, 1) CE8(2, 3) CE8(4, 5) CE8(6, 7)
        CE8(0, 2) CE8(1, 3) CE8(4, 6) CE8(5, 7)
        CE8(1, 2) CE8(5, 6)
        CE8(0, 4) CE8(1, 5) CE8(2, 6) CE8(3, 7)
        CE8(2, 4) CE8(3, 5)
        CE8(1, 2) CE8(3, 4) CE8(5, 6)
#undef CE8
        // bitonic half-clean: key[0..15] asc ++ [inf x8, s7..s0] desc;
        // lower 16 = key[0..7], fmin(key[8+i], s[7-i]) -> bitonic
#pragma unroll
        for (int j = 8; j < 16; ++j) key[j] = fmin(key[j], s[15 - j]);
        // bitonic clean of 16: stages 8,4,2,1
#pragma unroll
        for (int st = 8; st >= 1; st >>= 1) {
#pragma unroll
            for (int j = 0; j < KNN; ++j) {
                if ((j & st) == 0) {
                    double a = key[j], d = key[j | st];
                    key[j] = fmin(a, d);
                    key[j | st] = fmax(a, d);
                }
            }
        }
    }

    // layout [c][r][j]: lane writes 128 B contiguous, wave covers 8 KB
    u64* dst = pKey + ((size_t)c * RN + r) * KNN;
#pragma unroll
    for (int j = 0; j < KNN; ++j) dst[j] = (u64)__double_as_longlong(key[j]);
}

// ---- kernel 2: merge 32 sorted partial lists per row, 8 lanes per row ---
// Lane s bitonic-merges chunks [s*4, s*4+4), then 3 shfl_xor rounds
// combine the 8 sorted 16-lists. f64 min/max == exact u64 order (keys
// distinct -> total order, no stability concerns).
__global__ __launch_bounds__(256) void ef_knn_merge(const u64* __restrict__ pKey,
                                                    float* __restrict__ outIdxF) {
    int t = blockIdx.x * 256 + threadIdx.x;       // rows * MLANES = 131072
    int r = t >> 3;
    int s = t & 7;
    double key[KNN];
    {
        const u64* src = pKey + ((size_t)(s * MCH) * RN + r) * KNN;
#pragma unroll
        for (int j = 0; j < KNN; ++j)
            key[j] = __longlong_as_double((long long)src[j]);
    }
    for (int ci = 1; ci < MCH; ++ci) {
        const u64* src = pKey + ((size_t)(s * MCH + ci) * RN + r) * KNN;
        double v[KNN];
#pragma unroll
        for (int j = 0; j < KNN; ++j)
            v[j] = __longlong_as_double((long long)src[j]);
        // both sorted asc: half-clean keeps lower 16, then bitonic clean
#pragma unroll
        for (int j = 0; j < KNN; ++j) key[j] = fmin(key[j], v[KNN - 1 - j]);
#pragma unroll
        for (int st = 8; st >= 1; st >>= 1) {
#pragma unroll
            for (int j = 0; j < KNN; ++j) {
                if ((j & st) == 0) {
                    double a = key[j], d = key[j | st];
                    key[j] = fmin(a, d);
                    key[j | st] = fmax(a, d);
                }
            }
        }
    }
    // combine 8 lanes' sorted lists: rounds mask = 1, 2, 4
#pragma unroll
    for (int mask = 1; mask <= 4; mask <<= 1) {
        double oth[KNN];
#pragma unroll
        for (int j = 0; j < KNN; ++j) oth[j] = __shfl_xor(key[j], mask, 64);
#pragma unroll
        for (int j = 0; j < KNN; ++j) key[j] = fmin(key[j], oth[KNN - 1 - j]);
#pragma unroll
        for (int st = 8; st >= 1; st >>= 1) {
#pragma unroll
            for (int j = 0; j < KNN; ++j) {
                if ((j & st) == 0) {
                    double a = key[j], d = key[j | st];
                    key[j] = fmin(a, d);
                    key[j | st] = fmax(a, d);
                }
            }
        }
    }
    if (s == 0) {
        float* dstf = outIdxF + (size_t)r * KNN;
#pragma unroll
        for (int j = 0; j < KNN; ++j)
            dstf[j] = (float)(u32)((u64)__double_as_longlong(key[j]) & 0xFFFFFFFFu);
    }
}

// ---- kernel 3: edge features -------------------------------------------
// out[b][ch][n][k]: ch<64 -> central, ch>=64 -> neighbor - central.
__global__ __launch_bounds__(256) void ef_edge_kernel(const float* __restrict__ pc,
                                                      const float* __restrict__ idxF,
                                                      float* __restrict__ out) {
    int gid = blockIdx.x * 256 + threadIdx.x;      // B*N*K = 262144
    int b = gid >> 16;                             // N*K = 65536
    int nk = gid & 65535;
    int n = nk >> 4;
    int m = (int)idxF[gid];
    const float* pcb = pc + (size_t)b * DIMS * NPTS;
    float* ob = out + (size_t)b * 2 * DIMS * NPTS * KNN;
#pragma unroll
    for (int d = 0; d < DIMS; ++d) {
        float cv = pcb[(size_t)d * NPTS + n];
        float nv = pcb[(size_t)d * NPTS + m];
        ob[(size_t)d * (NPTS * KNN) + nk] = cv;
        ob[(size_t)(DIMS + d) * (NPTS * KNN) + nk] = nv - cv;
    }
}

extern "C" void kernel_launch(void* const* d_in, const int* in_sizes, int n_in,
                              void* d_out, int out_size, void* d_ws, size_t ws_size,
                              hipStream_t stream) {
    const float* pc = (const float*)d_in[0];
    float* out = (float*)d_out;

    // Scratch inside the edge-feature region of d_out (fully overwritten by
    // ef_edge_kernel): pKey 67.1 MB ++ sq 64 KB  (< 134 MB).
    u64* pKey = (u64*)d_out;                          // [NCHUNK][B*N][KNN] u64
    float* sq = out + 16777216;                       // byte 67,108,864
    float* outIdxF = out + (size_t)BATCH * 2 * DIMS * NPTS * KNN; // 33,554,432

    ef_sq_kernel<<<(BATCH * NPTS) / 256, 256, 0, stream>>>(pc, sq);
    ef_knn_partial<<<dim3((BATCH * NPTS) / 256, NCHUNK), 256, 0, stream>>>(pc, sq, pKey);
    ef_knn_merge<<<(BATCH * NPTS * MLANES) / 256, 256, 0, stream>>>(pKey, outIdxF);
    ef_edge_kernel<<<(BATCH * NPTS * KNN) / 256, 256, 0, stream>>>(pc, outIdxF, out);
}

// Round 4
// 325.117 us; speedup vs baseline: 4.3572x; 1.0344x over previous
//
#include <hip/hip_runtime.h>

// EdgeFeature kNN (DGCNN): B=4, D=64, N=4096, K=16, fp32 in/out.
// Ranking replicates the numpy fp32 reference pipeline bit-exactly:
//   sq_n  = numpy pairwise_sum (8-accumulator unroll) of fl(x_d^2)
//   dot   = sequential over d of  a = fmaf(x_d, y_d, a)   (einsum axpy w/ FMA)
//   d2    = fl(fl(sq_n + sq_m) - fl(2*dot));  dist = fl(sqrt(max(d2,0)))
//   order = (dist_f32, index) lexicographic (stable top_k tie-break)
// Key pack: (dist_bits << 32) | m. All packed keys are POSITIVE FINITE f64
// bit patterns, and for positive finite doubles numeric order == bit order,
// so v_min_f64/v_max_f64 give an exact 2-instr u64 compare-exchange.
// Sentinel = DBL_MAX bits 0x7FEFFFFFFFFFFFFF > any real key.
//
// R11 (from R10 counters: partial at ~50% of issue model, 3 waves/SIMD,
//      LDS-latency under-hidden; edge kernel ~100us from 4B gathers on
//      stride-16KB columns):
//   * partial: GSZ 8 -> 16. 16 independent FMA chains, 4 uniform
//     ds_read_b128 per d-step, sort16 = 2x sort8 (19 CE) + bitonic
//     merge (32 CE), then one key-merge per 16 cands. Same CE count per
//     candidate as R10 -- pure ILP/latency-hiding play.
//   * edge: neighbor/central rows read from pcT (transpose kernel is
//     back, pcT lives in d_ws -- NOT in d_out, which edge writes).
//     Thread owns 4 consecutive k: all I/O float4, 5x fewer mem instrs.
//     Fallback to the R10 edge kernel if ws_size is too small.

#define BATCH 4
#define DIMS 64
#define NPTS 4096
#define KNN 16
#define NCHUNK 32
#define CHLEN 128      // NPTS / NCHUNK
#define GSZ 16         // candidates per group: 16 independent FMA chains
#define RN (BATCH * NPTS)
#define MLANES 8       // merge lanes per row
#define MCH (NCHUNK / MLANES)

typedef unsigned long long u64;
typedef unsigned int u32;

__device__ __forceinline__ double sentinel() {
    return __longlong_as_double(0x7FEFFFFFFFFFFFFFLL);   // DBL_MAX bits
}

// ---- kernel 0: per-point squared norm, numpy pairwise_sum order ---------
__global__ __launch_bounds__(256) void ef_sq_kernel(const float* __restrict__ pc,
                                                    float* __restrict__ sq) {
    int gid = blockIdx.x * 256 + threadIdx.x;     // b*NPTS + n
    int b = gid >> 12;
    int n = gid & (NPTS - 1);
    const float* p = pc + (size_t)b * DIMS * NPTS + n;
    float r[8];
#pragma unroll
    for (int j = 0; j < 8; ++j) {
        float v = p[(size_t)j * NPTS];
        r[j] = __fmul_rn(v, v);
    }
#pragma unroll
    for (int i = 8; i < DIMS; i += 8) {
#pragma unroll
        for (int j = 0; j < 8; ++j) {
            float v = p[(size_t)(i + j) * NPTS];
            r[j] = __fadd_rn(r[j], __fmul_rn(v, v));
        }
    }
    float t01 = __fadd_rn(r[0], r[1]);
    float t23 = __fadd_rn(r[2], r[3]);
    float t45 = __fadd_rn(r[4], r[5]);
    float t67 = __fadd_rn(r[6], r[7]);
    sq[gid] = __fadd_rn(__fadd_rn(t01, t23), __fadd_rn(t45, t67));
}

// ---- kernel 0b: transpose pc[b][d][m] -> pcT[(b*N+m)*64+d] --------------
__global__ __launch_bounds__(256) void ef_transpose(const float* __restrict__ pc,
                                                    float* __restrict__ pcT) {
    __shared__ float smT[DIMS][65];               // 65: conflict-free both phases
    int tid = threadIdx.x;
    int m0 = blockIdx.x * 64;
    int b = blockIdx.y;
    const float* pcb = pc + (size_t)b * DIMS * NPTS;
#pragma unroll
    for (int i = 0; i < 16; ++i) {                // load: coalesced over m
        int idx = i * 256 + tid;
        int d = idx >> 6;
        int m = idx & 63;
        smT[d][m] = pcb[(size_t)d * NPTS + m0 + m];
    }
    __syncthreads();
#pragma unroll
    for (int i = 0; i < 16; ++i) {                // store: coalesced over d
        int idx = i * 256 + tid;
        int m = idx >> 6;
        int d = idx & 63;
        pcT[((size_t)b * NPTS + m0 + m) * DIMS + d] = smT[d][m];
    }
}

// ---- kernel 1: per-(row, chunk) partial top-16, LDS-staged candidates ---
__global__ __launch_bounds__(256, 3) void ef_knn_partial(const float* __restrict__ pc,
                                                         const float* __restrict__ sq,
                                                         u64* __restrict__ pKey) {
    __shared__ float tile[DIMS][CHLEN];           // 32 KB candidate tile
    __shared__ float tileSq[CHLEN];
    int tid = threadIdx.x;
    int r = blockIdx.x * 256 + tid;               // global row: b*NPTS + n
    int c = blockIdx.y;
    int b = (blockIdx.x * 256) >> 12;             // uniform per block
    int n = r & (NPTS - 1);
    int m0 = c * CHLEN;
    const float* pcb = pc + (size_t)b * DIMS * NPTS;

    // per-lane query row: lane n reads pc[b][d][n] -> coalesced across lanes
    float xr[DIMS];
#pragma unroll
    for (int d = 0; d < DIMS; ++d) xr[d] = pcb[(size_t)d * NPTS + n];
    // pin: forbid rematerialization (R9: compiler re-loaded xr per group)
#pragma unroll
    for (int d = 0; d < DIMS; ++d) asm volatile("" : "+v"(xr[d]));
    float sqn = sq[r];

    // stage candidate tile [64][128] + its sq row (coalesced float4)
#pragma unroll
    for (int i = 0; i < 8; ++i) {
        int idx = tid + i * 256;                  // float4 slot, 2048 total
        int d = idx >> 5;                         // 32 float4 per row
        int mq = idx & 31;
        float4 v = *(const float4*)(pcb + (size_t)d * NPTS + m0 + mq * 4);
        *(float4*)&tile[d][mq * 4] = v;
    }
    if (tid < CHLEN / 4)
        *(float4*)&tileSq[tid * 4] =
            *(const float4*)(sq + (size_t)b * NPTS + m0 + tid * 4);
    __syncthreads();

    double key[KNN];
#pragma unroll
    for (int j = 0; j < KNN; ++j) key[j] = sentinel();

#define CE(arr, i, jj) { double lo_ = fmin(arr[i], arr[jj]); double hi_ = fmax(arr[i], arr[jj]); arr[i] = lo_; arr[jj] = hi_; }

    for (int g = 0; g < CHLEN; g += GSZ) {
        float acc[GSZ];
#pragma unroll
        for (int j = 0; j < GSZ; ++j) acc[j] = 0.f;
        // d-major: four uniform ds_read_b128 per d-step (broadcast) feed 16
        // independent FMA chains; per-candidate d-order sequential (exact).
#pragma unroll
        for (int d = 0; d < DIMS; ++d) {
            float xv = xr[d];
            float4 q0 = *(const float4*)&tile[d][g];
            float4 q1 = *(const float4*)&tile[d][g + 4];
            float4 q2 = *(const float4*)&tile[d][g + 8];
            float4 q3 = *(const float4*)&tile[d][g + 12];
            acc[0]  = fmaf(xv, q0.x, acc[0]);
            acc[1]  = fmaf(xv, q0.y, acc[1]);
            acc[2]  = fmaf(xv, q0.z, acc[2]);
            acc[3]  = fmaf(xv, q0.w, acc[3]);
            acc[4]  = fmaf(xv, q1.x, acc[4]);
            acc[5]  = fmaf(xv, q1.y, acc[5]);
            acc[6]  = fmaf(xv, q1.z, acc[6]);
            acc[7]  = fmaf(xv, q1.w, acc[7]);
            acc[8]  = fmaf(xv, q2.x, acc[8]);
            acc[9]  = fmaf(xv, q2.y, acc[9]);
            acc[10] = fmaf(xv, q2.z, acc[10]);
            acc[11] = fmaf(xv, q2.w, acc[11]);
            acc[12] = fmaf(xv, q3.x, acc[12]);
            acc[13] = fmaf(xv, q3.y, acc[13]);
            acc[14] = fmaf(xv, q3.z, acc[14]);
            acc[15] = fmaf(xv, q3.w, acc[15]);
        }
        float4 s0 = *(const float4*)&tileSq[g];
        float4 s1 = *(const float4*)&tileSq[g + 4];
        float4 s2 = *(const float4*)&tileSq[g + 8];
        float4 s3 = *(const float4*)&tileSq[g + 12];
        float sqv[GSZ] = {s0.x, s0.y, s0.z, s0.w, s1.x, s1.y, s1.z, s1.w,
                          s2.x, s2.y, s2.z, s2.w, s3.x, s3.y, s3.z, s3.w};
        double s[GSZ];
#pragma unroll
        for (int j = 0; j < GSZ; ++j) {
            int m = m0 + g + j;
            float t1 = __fadd_rn(sqn, sqv[j]);
            float d2 = __fsub_rn(t1, __fmul_rn(2.0f, acc[j]));
            float dist = __fsqrt_rn(fmaxf(d2, 0.f));
            u64 cu = ((u64)__float_as_uint(dist) << 32) | (u64)(u32)m;
            double cand = __longlong_as_double((long long)cu);
            s[j] = (m == n) ? sentinel() : cand;   // self -> +max sentinel
        }
        // sort8 on s[0..7] and s[8..15]: Batcher odd-even mergesort, 19 CE
        CE(s, 0, 1) CE(s, 2, 3) CE(s, 4, 5) CE(s, 6, 7)
        CE(s, 0, 2) CE(s, 1, 3) CE(s, 4, 6) CE(s, 5, 7)
        CE(s, 1, 2) CE(s, 5, 6)
        CE(s, 0, 4) CE(s, 1, 5) CE(s, 2, 6) CE(s, 3, 7)
        CE(s, 2, 4) CE(s, 3, 5)
        CE(s, 1, 2) CE(s, 3, 4) CE(s, 5, 6)

        CE(s, 8, 9) CE(s, 10, 11) CE(s, 12, 13) CE(s, 14, 15)
        CE(s, 8, 10) CE(s, 9, 11) CE(s, 12, 14) CE(s, 13, 15)
        CE(s, 9, 10) CE(s, 13, 14)
        CE(s, 8, 12) CE(s, 9, 13) CE(s, 10, 14) CE(s, 11, 15)
        CE(s, 10, 12) CE(s, 11, 13)
        CE(s, 9, 10) CE(s, 11, 12) CE(s, 13, 14)

        // bitonic merge of two sorted-8s -> sorted 16 (8 + 24 CE)
        CE(s, 0, 15) CE(s, 1, 14) CE(s, 2, 13) CE(s, 3, 12)
        CE(s, 4, 11) CE(s, 5, 10) CE(s, 6, 9)  CE(s, 7, 8)
        CE(s, 0, 4)  CE(s, 1, 5)  CE(s, 2, 6)  CE(s, 3, 7)
        CE(s, 8, 12) CE(s, 9, 13) CE(s, 10, 14) CE(s, 11, 15)
        CE(s, 0, 2)  CE(s, 1, 3)  CE(s, 4, 6)  CE(s, 5, 7)
        CE(s, 8, 10) CE(s, 9, 11) CE(s, 12, 14) CE(s, 13, 15)
        CE(s, 0, 1)  CE(s, 2, 3)  CE(s, 4, 5)  CE(s, 6, 7)
        CE(s, 8, 9)  CE(s, 10, 11) CE(s, 12, 13) CE(s, 14, 15)

        // merge sorted s[16] into sorted key[16]: keep lowest 16 of 32
#pragma unroll
        for (int j = 0; j < KNN; ++j) key[j] = fmin(key[j], s[KNN - 1 - j]);
        // bitonic clean of 16: stages 8,4,2,1
#pragma unroll
        for (int st = 8; st >= 1; st >>= 1) {
#pragma unroll
            for (int j = 0; j < KNN; ++j) {
                if ((j & st) == 0) {
                    double a = key[j], d = key[j | st];
                    key[j] = fmin(a, d);
                    key[j | st] = fmax(a, d);
                }
            }
        }
    }
#undef CE

    // layout [c][r][j]: lane writes 128 B contiguous, wave covers 8 KB
    u64* dst = pKey + ((size_t)c * RN + r) * KNN;
#pragma unroll
    for (int j = 0; j < KNN; ++j) dst[j] = (u64)__double_as_longlong(key[j]);
}

// ---- kernel 2: merge 32 sorted partial lists per row, 8 lanes per row ---
__global__ __launch_bounds__(256) void ef_knn_merge(const u64* __restrict__ pKey,
                                                    float* __restrict__ outIdxF) {
    int t = blockIdx.x * 256 + threadIdx.x;       // rows * MLANES = 131072
    int r = t >> 3;
    int s = t & 7;
    double key[KNN];
    {
        const u64* src = pKey + ((size_t)(s * MCH) * RN + r) * KNN;
#pragma unroll
        for (int j = 0; j < KNN; ++j)
            key[j] = __longlong_as_double((long long)src[j]);
    }
    for (int ci = 1; ci < MCH; ++ci) {
        const u64* src = pKey + ((size_t)(s * MCH + ci) * RN + r) * KNN;
        double v[KNN];
#pragma unroll
        for (int j = 0; j < KNN; ++j)
            v[j] = __longlong_as_double((long long)src[j]);
#pragma unroll
        for (int j = 0; j < KNN; ++j) key[j] = fmin(key[j], v[KNN - 1 - j]);
#pragma unroll
        for (int st = 8; st >= 1; st >>= 1) {
#pragma unroll
            for (int j = 0; j < KNN; ++j) {
                if ((j & st) == 0) {
                    double a = key[j], d = key[j | st];
                    key[j] = fmin(a, d);
                    key[j | st] = fmax(a, d);
                }
            }
        }
    }
#pragma unroll
    for (int mask = 1; mask <= 4; mask <<= 1) {
        double oth[KNN];
#pragma unroll
        for (int j = 0; j < KNN; ++j) oth[j] = __shfl_xor(key[j], mask, 64);
#pragma unroll
        for (int j = 0; j < KNN; ++j) key[j] = fmin(key[j], oth[KNN - 1 - j]);
#pragma unroll
        for (int st = 8; st >= 1; st >>= 1) {
#pragma unroll
            for (int j = 0; j < KNN; ++j) {
                if ((j & st) == 0) {
                    double a = key[j], d = key[j | st];
                    key[j] = fmin(a, d);
                    key[j | st] = fmax(a, d);
                }
            }
        }
    }
    if (s == 0) {
        float* dstf = outIdxF + (size_t)r * KNN;
#pragma unroll
        for (int j = 0; j < KNN; ++j)
            dstf[j] = (float)(u32)((u64)__double_as_longlong(key[j]) & 0xFFFFFFFFu);
    }
}

// ---- kernel 3: edge features, pcT rows, 4 k per thread, float4 I/O ------
__global__ __launch_bounds__(256) void ef_edge_kernelT(const float* __restrict__ pcT,
                                                       const float* __restrict__ idxF,
                                                       float* __restrict__ out) {
    int t = blockIdx.x * 256 + threadIdx.x;        // B*N*K/4 = 65536
    int b = t >> 14;                               // N*K/4 = 16384
    int rem = t & 16383;
    int n = rem >> 2;
    int k0 = (rem & 3) * 4;
    float4 i4 = *(const float4*)(idxF + (((size_t)(b << 12) + n) << 4) + k0);
    int m0 = (int)i4.x, m1 = (int)i4.y, m2 = (int)i4.z, m3 = (int)i4.w;
    const float4* cr  = (const float4*)(pcT + ((size_t)(b << 12) + n)  * DIMS);
    const float4* nr0 = (const float4*)(pcT + ((size_t)(b << 12) + m0) * DIMS);
    const float4* nr1 = (const float4*)(pcT + ((size_t)(b << 12) + m1) * DIMS);
    const float4* nr2 = (const float4*)(pcT + ((size_t)(b << 12) + m2) * DIMS);
    const float4* nr3 = (const float4*)(pcT + ((size_t)(b << 12) + m3) * DIMS);
    float* ob = out + (size_t)b * 2 * DIMS * NPTS * KNN + (size_t)n * KNN + k0;
#pragma unroll
    for (int q = 0; q < DIMS / 4; ++q) {
        float4 c4 = cr[q];
        float4 a0 = nr0[q], a1 = nr1[q], a2 = nr2[q], a3 = nr3[q];
        float cv, nv0, nv1, nv2, nv3;
        float4 st;
        // d = 4q + dd, dd = 0..3
        cv = c4.x; nv0 = a0.x; nv1 = a1.x; nv2 = a2.x; nv3 = a3.x;
        st = make_float4(cv, cv, cv, cv);
        *(float4*)(ob + (size_t)(4 * q + 0) * (NPTS * KNN)) = st;
        st = make_float4(nv0 - cv, nv1 - cv, nv2 - cv, nv3 - cv);
        *(float4*)(ob + (size_t)(DIMS + 4 * q + 0) * (NPTS * KNN)) = st;
        cv = c4.y; nv0 = a0.y; nv1 = a1.y; nv2 = a2.y; nv3 = a3.y;
        st = make_float4(cv, cv, cv, cv);
        *(float4*)(ob + (size_t)(4 * q + 1) * (NPTS * KNN)) = st;
        st = make_float4(nv0 - cv, nv1 - cv, nv2 - cv, nv3 - cv);
        *(float4*)(ob + (size_t)(DIMS + 4 * q + 1) * (NPTS * KNN)) = st;
        cv = c4.z; nv0 = a0.z; nv1 = a1.z; nv2 = a2.z; nv3 = a3.z;
        st = make_float4(cv, cv, cv, cv);
        *(float4*)(ob + (size_t)(4 * q + 2) * (NPTS * KNN)) = st;
        st = make_float4(nv0 - cv, nv1 - cv, nv2 - cv, nv3 - cv);
        *(float4*)(ob + (size_t)(DIMS + 4 * q + 2) * (NPTS * KNN)) = st;
        cv = c4.w; nv0 = a0.w; nv1 = a1.w; nv2 = a2.w; nv3 = a3.w;
        st = make_float4(cv, cv, cv, cv);
        *(float4*)(ob + (size_t)(4 * q + 3) * (NPTS * KNN)) = st;
        st = make_float4(nv0 - cv, nv1 - cv, nv2 - cv, nv3 - cv);
        *(float4*)(ob + (size_t)(DIMS + 4 * q + 3) * (NPTS * KNN)) = st;
    }
}

// ---- kernel 3 fallback: edge features straight from pc (R10 version) ----
__global__ __launch_bounds__(256) void ef_edge_kernel(const float* __restrict__ pc,
                                                      const float* __restrict__ idxF,
                                                      float* __restrict__ out) {
    int gid = blockIdx.x * 256 + threadIdx.x;      // B*N*K = 262144
    int b = gid >> 16;                             // N*K = 65536
    int nk = gid & 65535;
    int n = nk >> 4;
    int m = (int)idxF[gid];
    const float* pcb = pc + (size_t)b * DIMS * NPTS;
    float* ob = out + (size_t)b * 2 * DIMS * NPTS * KNN;
#pragma unroll
    for (int d = 0; d < DIMS; ++d) {
        float cv = pcb[(size_t)d * NPTS + n];
        float nv = pcb[(size_t)d * NPTS + m];
        ob[(size_t)d * (NPTS * KNN) + nk] = cv;
        ob[(size_t)(DIMS + d) * (NPTS * KNN) + nk] = nv - cv;
    }
}

extern "C" void kernel_launch(void* const* d_in, const int* in_sizes, int n_in,
                              void* d_out, int out_size, void* d_ws, size_t ws_size,
                              hipStream_t stream) {
    const float* pc = (const float*)d_in[0];
    float* out = (float*)d_out;

    // Scratch inside the edge-feature region of d_out (fully overwritten by
    // the edge kernel): pKey 67.1 MB ++ sq 64 KB  (< 134 MB). pcT must NOT
    // live in d_out (edge reads it while writing d_out) -> d_ws.
    u64* pKey = (u64*)d_out;                          // [NCHUNK][B*N][KNN] u64
    float* sq = out + 16777216;                       // byte 67,108,864
    float* outIdxF = out + (size_t)BATCH * 2 * DIMS * NPTS * KNN; // final idx
    float* pcT = (float*)d_ws;                        // 16 MB
    bool useT = ws_size >= (size_t)BATCH * NPTS * DIMS * sizeof(float);

    ef_sq_kernel<<<(BATCH * NPTS) / 256, 256, 0, stream>>>(pc, sq);
    if (useT)
        ef_transpose<<<dim3(NPTS / 64, BATCH), 256, 0, stream>>>(pc, pcT);
    ef_knn_partial<<<dim3((BATCH * NPTS) / 256, NCHUNK), 256, 0, stream>>>(pc, sq, pKey);
    ef_knn_merge<<<(BATCH * NPTS * MLANES) / 256, 256, 0, stream>>>(pKey, outIdxF);
    if (useT)
        ef_edge_kernelT<<<(BATCH * NPTS * KNN / 4) / 256, 256, 0, stream>>>(pcT, outIdxF, out);
    else
        ef_edge_kernel<<<(BATCH * NPTS * KNN) / 256, 256, 0, stream>>>(pc, outIdxF, out);
}